// Round 1
// baseline (172.743 us; speedup 1.0000x reference)
//
#include <hip/hip_runtime.h>
#include <math.h>

#define BB 16
#define CC 256
#define HH 128
#define WW 128
#define HWSZ (HH * WW)   // 16384

// ---------------------------------------------------------------------------
// Kernel 1: channel-wise avg & max pool.
// Block = 256 threads = 32 float4-pixel-groups x 8 channel-splits.
// Each thread reduces 32 channels (float4 loads, stride HWSZ floats).
// Grid = 65536 f4-groups / 32 = 2048 blocks -> 32 waves/CU occupancy.
// ---------------------------------------------------------------------------
__global__ __launch_bounds__(256) void pool_kernel(const float* __restrict__ x,
                                                   float* __restrict__ avg_out,
                                                   float* __restrict__ max_out) {
    const int tf4   = threadIdx.x & 31;   // which f4 group in block
    const int split = threadIdx.x >> 5;   // 0..7 channel split
    const int g0    = blockIdx.x * 32;    // first f4 group of this block
    const int p0    = g0 * 4;             // first pixel of this block
    const int b     = p0 / HWSZ;          // whole block shares one batch idx
    const int hwb   = p0 % HWSZ;          // block's base pixel within plane
    const int hw    = hwb + tf4 * 4;

    const float* xb = x + (size_t)b * CC * HWSZ + hw;

    float4 s = make_float4(0.f, 0.f, 0.f, 0.f);
    float4 m = make_float4(-INFINITY, -INFINITY, -INFINITY, -INFINITY);

    const int c0 = split * 32;
    #pragma unroll 8
    for (int i = 0; i < 32; ++i) {
        float4 v = *(const float4*)(xb + (size_t)(c0 + i) * HWSZ);
        s.x += v.x; s.y += v.y; s.z += v.z; s.w += v.w;
        m.x = fmaxf(m.x, v.x); m.y = fmaxf(m.y, v.y);
        m.z = fmaxf(m.z, v.z); m.w = fmaxf(m.w, v.w);
    }

    __shared__ float4 sS[8][32];
    __shared__ float4 sM[8][32];
    sS[split][tf4] = s;
    sM[split][tf4] = m;
    __syncthreads();

    // tree-reduce across the 8 splits
    for (int off = 4; off >= 1; off >>= 1) {
        if (split < off) {
            float4 a  = sS[split][tf4], bb2 = sS[split + off][tf4];
            a.x += bb2.x; a.y += bb2.y; a.z += bb2.z; a.w += bb2.w;
            sS[split][tf4] = a;
            float4 ma = sM[split][tf4], mb = sM[split + off][tf4];
            ma.x = fmaxf(ma.x, mb.x); ma.y = fmaxf(ma.y, mb.y);
            ma.z = fmaxf(ma.z, mb.z); ma.w = fmaxf(ma.w, mb.w);
            sM[split][tf4] = ma;
        }
        __syncthreads();
    }

    if (split == 0) {
        float4 a = sS[0][tf4];
        const float inv = 1.0f / CC;
        a.x *= inv; a.y *= inv; a.z *= inv; a.w *= inv;
        *(float4*)(avg_out + (size_t)b * HWSZ + hw) = a;
        *(float4*)(max_out + (size_t)b * HWSZ + hw) = sM[0][tf4];
    }
}

// ---------------------------------------------------------------------------
// Kernel 2: 7x7 conv over [avg; max] planes + sigmoid -> M (16x128x128).
// One thread per output pixel. Pooled planes are 2 MB -> L2-resident.
// ---------------------------------------------------------------------------
__global__ __launch_bounds__(256) void conv_kernel(const float* __restrict__ avg_in,
                                                   const float* __restrict__ max_in,
                                                   const float* __restrict__ wgt,
                                                   float* __restrict__ Mout) {
    __shared__ float sw[98];
    if (threadIdx.x < 98) sw[threadIdx.x] = wgt[threadIdx.x];
    __syncthreads();

    const int idx = blockIdx.x * blockDim.x + threadIdx.x;  // 0 .. 262143
    const int b  = idx / HWSZ;
    const int hw = idx % HWSZ;
    const int h  = hw >> 7;
    const int w  = hw & 127;

    const float* ap = avg_in + (size_t)b * HWSZ;
    const float* mp = max_in + (size_t)b * HWSZ;

    float acc = 0.f;
    #pragma unroll
    for (int kh = 0; kh < 7; ++kh) {
        const int hh = h + kh - 3;
        if (hh < 0 || hh >= HH) continue;
        #pragma unroll
        for (int kw = 0; kw < 7; ++kw) {
            const int ww2 = w + kw - 3;
            if (ww2 < 0 || ww2 >= WW) continue;
            const int off = hh * WW + ww2;
            acc += ap[off] * sw[kh * 7 + kw];
            acc += mp[off] * sw[49 + kh * 7 + kw];
        }
    }
    Mout[idx] = 1.0f / (1.0f + expf(-acc));
}

// ---------------------------------------------------------------------------
// Kernel 3: out = x * M  (M broadcast over the 256 channels).
// float4 grid-stride streaming. M is 1 MB -> L2/L3-resident under reuse.
// ---------------------------------------------------------------------------
__global__ __launch_bounds__(256) void mul_kernel(const float* __restrict__ x,
                                                  const float* __restrict__ Mv,
                                                  float* __restrict__ out) {
    const int n4 = BB * CC * HWSZ / 4;  // 16,777,216
    const int stride = gridDim.x * blockDim.x;
    for (int i = blockIdx.x * blockDim.x + threadIdx.x; i < n4; i += stride) {
        const int b   = i >> 20;        // CC*HWSZ/4 = 2^20
        const int hw4 = i & 4095;       // HWSZ/4 = 4096
        float4 xv = ((const float4*)x)[i];
        float4 mv = *(const float4*)(Mv + (size_t)b * HWSZ + hw4 * 4);
        float4 o;
        o.x = xv.x * mv.x; o.y = xv.y * mv.y;
        o.z = xv.z * mv.z; o.w = xv.w * mv.w;
        ((float4*)out)[i] = o;
    }
}

extern "C" void kernel_launch(void* const* d_in, const int* in_sizes, int n_in,
                              void* d_out, int out_size, void* d_ws, size_t ws_size,
                              hipStream_t stream) {
    const float* x   = (const float*)d_in[0];
    const float* wgt = (const float*)d_in[1];
    float* out = (float*)d_out;

    float* avg_p = (float*)d_ws;                       // 16*16384 floats = 1 MB
    float* max_p = avg_p + (size_t)BB * HWSZ;          // 1 MB
    float* Mbuf  = max_p + (size_t)BB * HWSZ;          // 1 MB

    // 1) channel pool
    pool_kernel<<<2048, 256, 0, stream>>>(x, avg_p, max_p);

    // 2) 7x7 conv + sigmoid
    conv_kernel<<<(BB * HWSZ) / 256, 256, 0, stream>>>(avg_p, max_p, wgt, Mbuf);

    // 3) broadcast multiply
    mul_kernel<<<4096, 256, 0, stream>>>(x, Mbuf, out);
}

// Round 3
// 145.595 us; speedup vs baseline: 1.1865x; 1.1865x over previous
//
#include <hip/hip_runtime.h>
#include <math.h>

#define BB 16
#define CC 256
#define HH 128
#define WW 128
#define HWSZ (HH * WW)   // 16384

typedef float floatx4 __attribute__((ext_vector_type(4)));

// ---------------------------------------------------------------------------
// Kernel 1: channel-wise avg & max pool.
// Block = 256 threads = 32 float4-pixel-groups x 8 channel-splits.
// Each thread reduces 32 channels (float4 loads, stride HWSZ floats).
// Normal (caching) loads ON PURPOSE: x must be resident in L3 afterwards so
// mul_kernel's backward traversal can hit it.
// ---------------------------------------------------------------------------
__global__ __launch_bounds__(256) void pool_kernel(const float* __restrict__ x,
                                                   float* __restrict__ avg_out,
                                                   float* __restrict__ max_out) {
    const int tf4   = threadIdx.x & 31;   // which f4 group in block
    const int split = threadIdx.x >> 5;   // 0..7 channel split
    const int g0    = blockIdx.x * 32;    // first f4 group of this block
    const int p0    = g0 * 4;             // first pixel of this block
    const int b     = p0 / HWSZ;          // whole block shares one batch idx
    const int hwb   = p0 % HWSZ;          // block's base pixel within plane
    const int hw    = hwb + tf4 * 4;

    const float* xb = x + (size_t)b * CC * HWSZ + hw;

    float4 s = make_float4(0.f, 0.f, 0.f, 0.f);
    float4 m = make_float4(-INFINITY, -INFINITY, -INFINITY, -INFINITY);

    const int c0 = split * 32;
    #pragma unroll 8
    for (int i = 0; i < 32; ++i) {
        float4 v = *(const float4*)(xb + (size_t)(c0 + i) * HWSZ);
        s.x += v.x; s.y += v.y; s.z += v.z; s.w += v.w;
        m.x = fmaxf(m.x, v.x); m.y = fmaxf(m.y, v.y);
        m.z = fmaxf(m.z, v.z); m.w = fmaxf(m.w, v.w);
    }

    __shared__ float4 sS[8][32];
    __shared__ float4 sM[8][32];
    sS[split][tf4] = s;
    sM[split][tf4] = m;
    __syncthreads();

    // tree-reduce across the 8 splits
    for (int off = 4; off >= 1; off >>= 1) {
        if (split < off) {
            float4 a  = sS[split][tf4], bb2 = sS[split + off][tf4];
            a.x += bb2.x; a.y += bb2.y; a.z += bb2.z; a.w += bb2.w;
            sS[split][tf4] = a;
            float4 ma = sM[split][tf4], mb = sM[split + off][tf4];
            ma.x = fmaxf(ma.x, mb.x); ma.y = fmaxf(ma.y, mb.y);
            ma.z = fmaxf(ma.z, mb.z); ma.w = fmaxf(ma.w, mb.w);
            sM[split][tf4] = ma;
        }
        __syncthreads();
    }

    if (split == 0) {
        float4 a = sS[0][tf4];
        const float inv = 1.0f / CC;
        a.x *= inv; a.y *= inv; a.z *= inv; a.w *= inv;
        *(float4*)(avg_out + (size_t)b * HWSZ + hw) = a;
        *(float4*)(max_out + (size_t)b * HWSZ + hw) = sM[0][tf4];
    }
}

// ---------------------------------------------------------------------------
// Kernel 2: 7x7 conv over [avg; max] planes + sigmoid -> M (16x128x128).
// One thread per output pixel. Pooled planes are 2 MB total -> L2-resident.
// ---------------------------------------------------------------------------
__global__ __launch_bounds__(256) void conv_kernel(const float* __restrict__ avg_in,
                                                   const float* __restrict__ max_in,
                                                   const float* __restrict__ wgt,
                                                   float* __restrict__ Mout) {
    __shared__ float sw[98];
    if (threadIdx.x < 98) sw[threadIdx.x] = wgt[threadIdx.x];
    __syncthreads();

    const int idx = blockIdx.x * blockDim.x + threadIdx.x;  // 0 .. 262143
    const int b  = idx / HWSZ;
    const int hw = idx % HWSZ;
    const int h  = hw >> 7;
    const int w  = hw & 127;

    const float* ap = avg_in + (size_t)b * HWSZ;
    const float* mp = max_in + (size_t)b * HWSZ;

    float acc = 0.f;
    #pragma unroll
    for (int kh = 0; kh < 7; ++kh) {
        const int hh = h + kh - 3;
        if (hh < 0 || hh >= HH) continue;
        #pragma unroll
        for (int kw = 0; kw < 7; ++kw) {
            const int ww2 = w + kw - 3;
            if (ww2 < 0 || ww2 >= WW) continue;
            const int off = hh * WW + ww2;
            acc += ap[off] * sw[kh * 7 + kw];
            acc += mp[off] * sw[49 + kh * 7 + kw];
        }
    }
    Mout[idx] = 1.0f / (1.0f + expf(-acc));
}

// ---------------------------------------------------------------------------
// Kernel 3: out = x * M, traversed BACKWARDS so the x tail (still resident in
// the 256 MiB Infinity Cache from pool_kernel's forward stream) is hit
// most-recently-used-first. Nontemporal loads (last use of x, don't
// re-allocate) + nontemporal stores (out must not evict x from L3).
// Grid is exactly 4096x256 and n4 % stride == 0 -> no bounds checks.
// ---------------------------------------------------------------------------
__global__ __launch_bounds__(256) void mul_kernel(const float* __restrict__ x,
                                                  const float* __restrict__ Mv,
                                                  float* __restrict__ out) {
    const int n4     = BB * CC * HWSZ / 4;          // 16,777,216
    const int stride = gridDim.x * blockDim.x;      // 1,048,576
    const int rbid   = gridDim.x - 1 - blockIdx.x;  // earliest blocks -> highest addrs
    const int base   = rbid * blockDim.x + threadIdx.x;
    const int nIter  = n4 / stride;                 // 16 exactly

    const floatx4* xv4 = (const floatx4*)x;
    floatx4*       ov4 = (floatx4*)out;

    for (int it = nIter - 1; it >= 0; --it) {
        const int i   = it * stride + base;
        const int b   = i >> 20;                    // CC*HWSZ/4 = 2^20
        const int hw4 = i & 4095;                   // HWSZ/4 = 4096
        floatx4 xv = __builtin_nontemporal_load(xv4 + i);
        floatx4 mv = *(const floatx4*)(Mv + (size_t)b * HWSZ + (size_t)hw4 * 4);
        floatx4 o  = xv * mv;
        __builtin_nontemporal_store(o, ov4 + i);
    }
}

extern "C" void kernel_launch(void* const* d_in, const int* in_sizes, int n_in,
                              void* d_out, int out_size, void* d_ws, size_t ws_size,
                              hipStream_t stream) {
    const float* x   = (const float*)d_in[0];
    const float* wgt = (const float*)d_in[1];
    float* out = (float*)d_out;

    float* avg_p = (float*)d_ws;                       // 16*16384 floats = 1 MB
    float* max_p = avg_p + (size_t)BB * HWSZ;          // 1 MB
    float* Mbuf  = max_p + (size_t)BB * HWSZ;          // 1 MB

    // 1) channel pool
    pool_kernel<<<2048, 256, 0, stream>>>(x, avg_p, max_p);

    // 2) 7x7 conv + sigmoid
    conv_kernel<<<(BB * HWSZ) / 256, 256, 0, stream>>>(avg_p, max_p, wgt, Mbuf);

    // 3) broadcast multiply (backward, nontemporal)
    mul_kernel<<<4096, 256, 0, stream>>>(x, Mbuf, out);
}